// Round 1
// baseline (14576.460 us; speedup 1.0000x reference)
//
#include <hip/hip_runtime.h>

#define BATCH 128
#define TT    512
#define HH    256
#define G4    1024   // 4*H

// One workgroup per batch row; thread j owns gate-row j of W_hh in registers.
// h lives in LDS; per step: gates = W_hh @ h (+ x_t*W_ih + bias), then
// threads j<256 apply the LSTM cell update and publish new h.
__global__ __launch_bounds__(1024) void lstm_fused(
    const float* __restrict__ x,      // [B,T]
    const float* __restrict__ W_ih,   // [1024]
    const float* __restrict__ W_hh,   // [1024,256]
    const float* __restrict__ b_ih,   // [1024]
    const float* __restrict__ b_hh,   // [1024]
    const float* __restrict__ W1,     // [128,256]
    const float* __restrict__ b1,     // [128]
    const float* __restrict__ W2,     // [128]
    const float* __restrict__ b2,     // [1]
    float* __restrict__ out)          // [B]
{
    const int b = blockIdx.x;
    const int j = threadIdx.x;

    __shared__ __align__(16) float x_lds[TT];
    __shared__ __align__(16) float h_lds[HH];
    __shared__ __align__(16) float gates_lds[G4];
    __shared__ __align__(16) float red_lds[128];

    // --- load my W_hh row into registers (one-time, L2/L3 cached across wgs)
    float w[HH];
    {
        const float4* wrow = reinterpret_cast<const float4*>(W_hh + (size_t)j * HH);
        #pragma unroll
        for (int k4 = 0; k4 < HH / 4; ++k4) {
            float4 v = wrow[k4];
            w[4 * k4 + 0] = v.x;
            w[4 * k4 + 1] = v.y;
            w[4 * k4 + 2] = v.z;
            w[4 * k4 + 3] = v.w;
        }
    }
    const float wih  = W_ih[j];
    const float bias = b_ih[j] + b_hh[j];

    if (j < TT) x_lds[j] = x[(size_t)b * TT + j];
    if (j < HH) h_lds[j] = 0.0f;
    float c = 0.0f;
    __syncthreads();

    for (int t = 0; t < TT; ++t) {
        // --- phase 1: gate pre-activations, all 1024 threads
        float a0 = 0.f, a1 = 0.f, a2 = 0.f, a3 = 0.f;
        const float4* h4 = reinterpret_cast<const float4*>(h_lds);
        #pragma unroll
        for (int k4 = 0; k4 < HH / 4; ++k4) {
            float4 hv = h4[k4];               // wave-broadcast ds_read_b128
            a0 = __builtin_fmaf(w[4 * k4 + 0], hv.x, a0);
            a1 = __builtin_fmaf(w[4 * k4 + 1], hv.y, a1);
            a2 = __builtin_fmaf(w[4 * k4 + 2], hv.z, a2);
            a3 = __builtin_fmaf(w[4 * k4 + 3], hv.w, a3);
        }
        gates_lds[j] = (a0 + a1) + (a2 + a3) + __builtin_fmaf(x_lds[t], wih, bias);
        __syncthreads();

        // --- phase 2: cell update, threads 0..255 (waves 0-3, one per SIMD)
        if (j < HH) {
            float ig = gates_lds[j];
            float fg = gates_lds[j + HH];
            float gg = gates_lds[j + 2 * HH];
            float og = gates_lds[j + 3 * HH];
            // sigmoid(v) = 1/(1+e^-v); tanh(v) = 2/(1+e^-2v) - 1  (fast v_exp/v_rcp)
            ig = __builtin_amdgcn_rcpf(1.f + __expf(-ig));
            fg = __builtin_amdgcn_rcpf(1.f + __expf(-fg));
            og = __builtin_amdgcn_rcpf(1.f + __expf(-og));
            gg = 2.f * __builtin_amdgcn_rcpf(1.f + __expf(-2.f * gg)) - 1.f;
            c = __builtin_fmaf(fg, c, ig * gg);
            float th = 2.f * __builtin_amdgcn_rcpf(1.f + __expf(-2.f * c)) - 1.f;
            h_lds[j] = og * th;
        }
        __syncthreads();
    }

    // --- epilogue MLP: y = relu(h @ W1.T + b1) @ W2.T + b2
    if (j < 128) {
        const float4* w1row = reinterpret_cast<const float4*>(W1 + (size_t)j * HH);
        const float4* h4    = reinterpret_cast<const float4*>(h_lds);
        float s0 = 0.f, s1 = 0.f, s2 = 0.f, s3 = 0.f;
        #pragma unroll
        for (int k4 = 0; k4 < HH / 4; ++k4) {
            float4 wv = w1row[k4];
            float4 hv = h4[k4];
            s0 = __builtin_fmaf(wv.x, hv.x, s0);
            s1 = __builtin_fmaf(wv.y, hv.y, s1);
            s2 = __builtin_fmaf(wv.z, hv.z, s2);
            s3 = __builtin_fmaf(wv.w, hv.w, s3);
        }
        float r = (s0 + s1) + (s2 + s3) + b1[j];
        r = fmaxf(r, 0.f);
        red_lds[j] = r * W2[j];
    }
    __syncthreads();
    if (j == 0) {
        float y = b2[0];
        #pragma unroll 4
        for (int k = 0; k < 128; ++k) y += red_lds[k];
        out[b] = y;
    }
}

extern "C" void kernel_launch(void* const* d_in, const int* in_sizes, int n_in,
                              void* d_out, int out_size, void* d_ws, size_t ws_size,
                              hipStream_t stream) {
    const float* x    = (const float*)d_in[0];
    const float* W_ih = (const float*)d_in[1];
    const float* W_hh = (const float*)d_in[2];
    const float* b_ih = (const float*)d_in[3];
    const float* b_hh = (const float*)d_in[4];
    const float* W1   = (const float*)d_in[5];
    const float* b1   = (const float*)d_in[6];
    const float* W2   = (const float*)d_in[7];
    const float* b2   = (const float*)d_in[8];
    float* out = (float*)d_out;

    lstm_fused<<<BATCH, 1024, 0, stream>>>(x, W_ih, W_hh, b_ih, b_hh,
                                           W1, b1, W2, b2, out);
}

// Round 2
// 5524.136 us; speedup vs baseline: 2.6387x; 2.6387x over previous
//
#include <hip/hip_runtime.h>

#define TT 512
#define HH 256
#define BB 128

// 256 wgs x 1024 threads, cooperative. Group g = wgs 4g..4g+3 handles
// batches {2g, 2g+1}. wg q owns h elements [64q, 64q+64): gate rows
// G*256 + 64q + [0,64) for G in {i,f,g,o}. Thread holds 2 rows x 32-K-chunk
// of W_hh in 64 VGPRs. Per step: dot -> LDS reduce -> cell update ->
// publish h-slice to global (agent scope) -> group barrier -> import h.
__global__ __launch_bounds__(1024, 4) void lstm_coop(
    const float* __restrict__ x,      // [B,T]
    const float* __restrict__ W_ih,   // [1024]
    const float* __restrict__ W_hh,   // [1024,256]
    const float* __restrict__ b_ih,   // [1024]
    const float* __restrict__ b_hh,   // [1024]
    const float* __restrict__ W1,     // [128,256]
    const float* __restrict__ b1,     // [128]
    const float* __restrict__ W2,     // [128]
    const float* __restrict__ b2,     // [1]
    float* __restrict__ out,          // [B]
    int* __restrict__ ctrs,           // [64] stride 16 ints
    float* __restrict__ hbuf)         // [2][BB][HH]
{
    const int wg  = blockIdx.x;
    const int g   = wg >> 2;
    const int q   = wg & 3;
    const int tid = threadIdx.x;
    const int b0  = 2 * g;

    __shared__ float x_lds[2][TT];        // 4 KB
    __shared__ float h_lds[2][HH];        // 2 KB
    __shared__ float part_lds[16][HH];    // 16 KB  [m*8+s][row]
    __shared__ float pre_lds[2][HH];      // 2 KB

    // dot-phase mapping: s = k-chunk (8 chunks of 32), r2 = row-pair id
    const int s  = tid >> 7;          // 0..7
    const int r2 = tid & 127;         // 0..127 -> rows r2 and r2+128
    // global gate rows for my two local rows
    const int RA = ((r2 >> 6)    ) * HH + q * 64 + (r2 & 63);      // gates i/f
    const int RB = ((r2 >> 6) + 2) * HH + q * 64 + (r2 & 63);      // gates g/o

    // resident weights: W_hh[RA][32s..32s+31], W_hh[RB][...]
    float wa[32], wb[32];
    {
        const float4* pa = reinterpret_cast<const float4*>(W_hh + (size_t)RA * HH + 32 * s);
        const float4* pb = reinterpret_cast<const float4*>(W_hh + (size_t)RB * HH + 32 * s);
        #pragma unroll
        for (int k = 0; k < 8; ++k) {
            float4 va = pa[k], vb = pb[k];
            wa[4*k+0] = va.x; wa[4*k+1] = va.y; wa[4*k+2] = va.z; wa[4*k+3] = va.w;
            wb[4*k+0] = vb.x; wb[4*k+1] = vb.y; wb[4*k+2] = vb.z; wb[4*k+3] = vb.w;
        }
    }

    // reduce-phase per-row constants (row = tid&255, used by tid<512)
    const int rr_row = tid & 255;
    const int RR = (rr_row >> 6) * HH + q * 64 + (rr_row & 63);
    const float wih_r  = W_ih[RR];
    const float bias_r = b_ih[RR] + b_hh[RR];

    // stage x for both batches
    {
        int m = tid >> 9, j = tid & 511;
        x_lds[m][j] = x[(size_t)(b0 + m) * TT + j];
    }
    if (tid < 512) h_lds[tid >> 8][tid & 255] = 0.0f;

    float c = 0.0f;                       // cell state for tid<128
    int* ctrp = ctrs + g * 16;
    int target = 0;
    __syncthreads();

    for (int t = 0; t < TT; ++t) {
        // ---- dot: all 1024 threads, 128 fma each
        const float4* ha = reinterpret_cast<const float4*>(&h_lds[0][32 * s]);
        const float4* hb = reinterpret_cast<const float4*>(&h_lds[1][32 * s]);
        float aA0 = 0.f, aA1 = 0.f, bA0 = 0.f, bA1 = 0.f;
        #pragma unroll
        for (int k = 0; k < 8; ++k) {
            float4 h0 = ha[k];
            float4 h1 = hb[k];
            aA0 = __builtin_fmaf(wa[4*k+0], h0.x, aA0);
            aA0 = __builtin_fmaf(wa[4*k+1], h0.y, aA0);
            aA0 = __builtin_fmaf(wa[4*k+2], h0.z, aA0);
            aA0 = __builtin_fmaf(wa[4*k+3], h0.w, aA0);
            aA1 = __builtin_fmaf(wb[4*k+0], h0.x, aA1);
            aA1 = __builtin_fmaf(wb[4*k+1], h0.y, aA1);
            aA1 = __builtin_fmaf(wb[4*k+2], h0.z, aA1);
            aA1 = __builtin_fmaf(wb[4*k+3], h0.w, aA1);
            bA0 = __builtin_fmaf(wa[4*k+0], h1.x, bA0);
            bA0 = __builtin_fmaf(wa[4*k+1], h1.y, bA0);
            bA0 = __builtin_fmaf(wa[4*k+2], h1.z, bA0);
            bA0 = __builtin_fmaf(wa[4*k+3], h1.w, bA0);
            bA1 = __builtin_fmaf(wb[4*k+0], h1.x, bA1);
            bA1 = __builtin_fmaf(wb[4*k+1], h1.y, bA1);
            bA1 = __builtin_fmaf(wb[4*k+2], h1.z, bA1);
            bA1 = __builtin_fmaf(wb[4*k+3], h1.w, bA1);
        }
        part_lds[s][r2]           = aA0;   // batch0, row r2
        part_lds[s][r2 + 128]     = aA1;   // batch0, row r2+128
        part_lds[8 + s][r2]       = bA0;   // batch1
        part_lds[8 + s][r2 + 128] = bA1;
        __syncthreads();

        // ---- reduce over 8 k-chunks + input/bias: tid<512
        if (tid < 512) {
            int m = tid >> 8;
            float v = 0.f;
            #pragma unroll
            for (int ss = 0; ss < 8; ++ss) v += part_lds[m * 8 + ss][rr_row];
            pre_lds[m][rr_row] = v + __builtin_fmaf(x_lds[m][t], wih_r, bias_r);
        }
        __syncthreads();

        // ---- cell update: tid<128 (m = tid>>6, local elem l2 = tid&63)
        if (tid < 128) {
            int m  = tid >> 6;
            int l2 = tid & 63;
            float ig = pre_lds[m][l2];
            float fg = pre_lds[m][64 + l2];
            float gg = pre_lds[m][128 + l2];
            float og = pre_lds[m][192 + l2];
            ig = __builtin_amdgcn_rcpf(1.f + __expf(-ig));
            fg = __builtin_amdgcn_rcpf(1.f + __expf(-fg));
            og = __builtin_amdgcn_rcpf(1.f + __expf(-og));
            gg = 2.f * __builtin_amdgcn_rcpf(1.f + __expf(-2.f * gg)) - 1.f;
            c = __builtin_fmaf(fg, c, ig * gg);
            float th = 2.f * __builtin_amdgcn_rcpf(1.f + __expf(-2.f * c)) - 1.f;
            float hn = og * th;
            int e = q * 64 + l2;
            h_lds[m][e] = hn;
            int p = (t + 1) & 1;
            __hip_atomic_store(&hbuf[((size_t)p * BB + (b0 + m)) * HH + e], hn,
                               __ATOMIC_RELAXED, __HIP_MEMORY_SCOPE_AGENT);
        }
        __syncthreads();   // drains vmcnt: agent-scope stores are visible

        // ---- group barrier
        target += 4;
        if (tid == 0) {
            __threadfence();
            __hip_atomic_fetch_add(ctrp, 1, __ATOMIC_RELEASE, __HIP_MEMORY_SCOPE_AGENT);
            while (__hip_atomic_load(ctrp, __ATOMIC_ACQUIRE, __HIP_MEMORY_SCOPE_AGENT) < target)
                __builtin_amdgcn_s_sleep(1);
        }
        __syncthreads();

        // ---- import full h for both batches
        if (tid < 512) {
            int p = (t + 1) & 1;
            int m = tid >> 8, j = tid & 255;
            h_lds[m][j] = __hip_atomic_load(&hbuf[((size_t)p * BB + (b0 + m)) * HH + j],
                                            __ATOMIC_RELAXED, __HIP_MEMORY_SCOPE_AGENT);
        }
        __syncthreads();
    }

    // ---- epilogue MLP, done by q==0 wg of each group for its 2 batches
    if (q == 0) {
        if (tid < 256) {
            int m = tid >> 7, j = tid & 127;
            const float4* w1p = reinterpret_cast<const float4*>(W1 + (size_t)j * HH);
            const float4* hp  = reinterpret_cast<const float4*>(&h_lds[m][0]);
            float s0 = 0.f, s1 = 0.f;
            #pragma unroll
            for (int k = 0; k < 64; ++k) {
                float4 wv = w1p[k], hv = hp[k];
                s0 = __builtin_fmaf(wv.x, hv.x, s0);
                s1 = __builtin_fmaf(wv.y, hv.y, s1);
                s0 = __builtin_fmaf(wv.z, hv.z, s0);
                s1 = __builtin_fmaf(wv.w, hv.w, s1);
            }
            float rv = fmaxf(s0 + s1 + b1[j], 0.f);
            part_lds[0][m * 128 + j] = rv * W2[j];
        }
        __syncthreads();
        if (tid < 2) {
            float y = b2[0];
            for (int k = 0; k < 128; ++k) y += part_lds[0][tid * 128 + k];
            out[b0 + tid] = y;
        }
    }
}

extern "C" void kernel_launch(void* const* d_in, const int* in_sizes, int n_in,
                              void* d_out, int out_size, void* d_ws, size_t ws_size,
                              hipStream_t stream) {
    const float* x    = (const float*)d_in[0];
    const float* W_ih = (const float*)d_in[1];
    const float* W_hh = (const float*)d_in[2];
    const float* b_ih = (const float*)d_in[3];
    const float* b_hh = (const float*)d_in[4];
    const float* W1   = (const float*)d_in[5];
    const float* b1   = (const float*)d_in[6];
    const float* W2   = (const float*)d_in[7];
    const float* b2   = (const float*)d_in[8];
    float* out  = (float*)d_out;

    int*   ctrs = (int*)d_ws;                          // 4 KB (64 ctrs, stride 64B)
    float* hbuf = (float*)((char*)d_ws + 4096);        // 2*128*256*4 = 256 KB

    // counters must be zero at every call (d_ws is not re-poisoned between replays)
    hipMemsetAsync(d_ws, 0, 4096, stream);

    void* args[] = {(void*)&x, (void*)&W_ih, (void*)&W_hh, (void*)&b_ih, (void*)&b_hh,
                    (void*)&W1, (void*)&b1, (void*)&W2, (void*)&b2,
                    (void*)&out, (void*)&ctrs, (void*)&hbuf};
    hipLaunchCooperativeKernel((void*)lstm_coop, dim3(256), dim3(1024), args, 0, stream);
}

// Round 3
// 4975.246 us; speedup vs baseline: 2.9298x; 1.1103x over previous
//
#include <hip/hip_runtime.h>

#define TT 512
#define HH 256
#define BB 128

// 256 wgs x 1024 threads, cooperative. Group g (g = wg & 63) = wgs
// {g, g+64, g+128, g+192} (same XCD under round-robin dispatch), handles
// batches {2g, 2g+1}. Member q = wg >> 6 owns h elements [64q, 64q+64):
// gate rows G*256 + 64q + [0,64) for G in {i,f,g,o}. Thread holds
// 2 rows x 32-K-chunk of W_hh in 64 VGPRs (pinned: waves_per_eu(4,4) +
// asm opacity so the compiler can neither spill-target-64 nor remat).
// Per step: dot -> LDS reduce -> cell update -> publish h-slice (agent
// scope) -> epoch-flag barrier -> import h.
__global__ __launch_bounds__(1024)
__attribute__((amdgpu_waves_per_eu(4, 4)))
void lstm_coop(
    const float* __restrict__ x,      // [B,T]
    const float* __restrict__ W_ih,   // [1024]
    const float* __restrict__ W_hh,   // [1024,256]
    const float* __restrict__ b_ih,   // [1024]
    const float* __restrict__ b_hh,   // [1024]
    const float* __restrict__ W1,     // [128,256]
    const float* __restrict__ b1,     // [128]
    const float* __restrict__ W2,     // [128]
    const float* __restrict__ b2,     // [1]
    float* __restrict__ out,          // [B]
    int* __restrict__ flags,          // [256] stride-16 ints (epoch per wg)
    float* __restrict__ hbuf)         // [2][BB][HH]
{
    const int wg  = blockIdx.x;
    const int g   = wg & 63;          // group id (batch pair)
    const int q   = wg >> 6;          // member id 0..3
    const int tid = threadIdx.x;
    const int b0  = 2 * g;

    __shared__ float x_lds[2][TT];        // 4 KB
    __shared__ float h_lds[2][HH];        // 2 KB
    __shared__ float part_lds[16][HH];    // 16 KB  [m*8+s][row]
    __shared__ float pre_lds[2][HH];      // 2 KB

    // dot-phase mapping: s = k-chunk (8 chunks of 32), r2 = row-pair id
    const int s  = tid >> 7;          // 0..7
    const int r2 = tid & 127;         // 0..127 -> rows r2 and r2+128
    const int RA = ((r2 >> 6)    ) * HH + q * 64 + (r2 & 63);      // gates i/f
    const int RB = ((r2 >> 6) + 2) * HH + q * 64 + (r2 & 63);      // gates g/o

    // resident weights: W_hh[RA][32s..32s+31], W_hh[RB][...]
    float wa[32], wb[32];
    {
        const float4* pa = reinterpret_cast<const float4*>(W_hh + (size_t)RA * HH + 32 * s);
        const float4* pb = reinterpret_cast<const float4*>(W_hh + (size_t)RB * HH + 32 * s);
        #pragma unroll
        for (int k = 0; k < 8; ++k) {
            float4 va = pa[k], vb = pb[k];
            wa[4*k+0] = va.x; wa[4*k+1] = va.y; wa[4*k+2] = va.z; wa[4*k+3] = va.w;
            wb[4*k+0] = vb.x; wb[4*k+1] = vb.y; wb[4*k+2] = vb.z; wb[4*k+3] = vb.w;
        }
    }
    // make weight values opaque: cannot be rematerialized from W_hh
    #pragma unroll
    for (int k = 0; k < 32; ++k) {
        asm volatile("" : "+v"(wa[k]));
        asm volatile("" : "+v"(wb[k]));
    }

    // reduce-phase per-row constants (row = tid&255, used by tid<512)
    const int rr_row = tid & 255;
    const int RR = (rr_row >> 6) * HH + q * 64 + (rr_row & 63);
    const float wih_r  = W_ih[RR];
    const float bias_r = b_ih[RR] + b_hh[RR];

    // stage x for both batches
    {
        int m = tid >> 9, j = tid & 511;
        x_lds[m][j] = x[(size_t)(b0 + m) * TT + j];
    }
    if (tid < 512) h_lds[tid >> 8][tid & 255] = 0.0f;

    float c = 0.0f;                       // cell state for tid<128
    __syncthreads();

    for (int t = 0; t < TT; ++t) {
        // ---- dot: all 1024 threads, 128 fma each
        const float4* ha = reinterpret_cast<const float4*>(&h_lds[0][32 * s]);
        const float4* hb = reinterpret_cast<const float4*>(&h_lds[1][32 * s]);
        float aA0 = 0.f, aA1 = 0.f, bA0 = 0.f, bA1 = 0.f;
        #pragma unroll
        for (int k = 0; k < 8; ++k) {
            float4 h0 = ha[k];
            float4 h1 = hb[k];
            aA0 = __builtin_fmaf(wa[4*k+0], h0.x, aA0);
            aA0 = __builtin_fmaf(wa[4*k+1], h0.y, aA0);
            aA0 = __builtin_fmaf(wa[4*k+2], h0.z, aA0);
            aA0 = __builtin_fmaf(wa[4*k+3], h0.w, aA0);
            aA1 = __builtin_fmaf(wb[4*k+0], h0.x, aA1);
            aA1 = __builtin_fmaf(wb[4*k+1], h0.y, aA1);
            aA1 = __builtin_fmaf(wb[4*k+2], h0.z, aA1);
            aA1 = __builtin_fmaf(wb[4*k+3], h0.w, aA1);
            bA0 = __builtin_fmaf(wa[4*k+0], h1.x, bA0);
            bA0 = __builtin_fmaf(wa[4*k+1], h1.y, bA0);
            bA0 = __builtin_fmaf(wa[4*k+2], h1.z, bA0);
            bA0 = __builtin_fmaf(wa[4*k+3], h1.w, bA0);
            bA1 = __builtin_fmaf(wb[4*k+0], h1.x, bA1);
            bA1 = __builtin_fmaf(wb[4*k+1], h1.y, bA1);
            bA1 = __builtin_fmaf(wb[4*k+2], h1.z, bA1);
            bA1 = __builtin_fmaf(wb[4*k+3], h1.w, bA1);
        }
        part_lds[s][r2]           = aA0;   // batch0, row r2
        part_lds[s][r2 + 128]     = aA1;   // batch0, row r2+128
        part_lds[8 + s][r2]       = bA0;   // batch1
        part_lds[8 + s][r2 + 128] = bA1;
        __syncthreads();

        // ---- reduce over 8 k-chunks + input/bias: tid<512
        if (tid < 512) {
            int m = tid >> 8;
            float v = 0.f;
            #pragma unroll
            for (int ss = 0; ss < 8; ++ss) v += part_lds[m * 8 + ss][rr_row];
            pre_lds[m][rr_row] = v + __builtin_fmaf(x_lds[m][t], wih_r, bias_r);
        }
        __syncthreads();

        // ---- cell update: tid<128 (m = tid>>6, local elem l2 = tid&63)
        if (tid < 128) {
            int m  = tid >> 6;
            int l2 = tid & 63;
            float ig = pre_lds[m][l2];
            float fg = pre_lds[m][64 + l2];
            float gg = pre_lds[m][128 + l2];
            float og = pre_lds[m][192 + l2];
            ig = __builtin_amdgcn_rcpf(1.f + __expf(-ig));
            fg = __builtin_amdgcn_rcpf(1.f + __expf(-fg));
            og = __builtin_amdgcn_rcpf(1.f + __expf(-og));
            gg = 2.f * __builtin_amdgcn_rcpf(1.f + __expf(-2.f * gg)) - 1.f;
            c = __builtin_fmaf(fg, c, ig * gg);
            float th = 2.f * __builtin_amdgcn_rcpf(1.f + __expf(-2.f * c)) - 1.f;
            float hn = og * th;
            int e = q * 64 + l2;
            h_lds[m][e] = hn;
            int p = (t + 1) & 1;
            __hip_atomic_store(&hbuf[((size_t)p * BB + (b0 + m)) * HH + e], hn,
                               __ATOMIC_RELAXED, __HIP_MEMORY_SCOPE_AGENT);
        }
        __syncthreads();   // all h-stores issued and drained (vmcnt) per-thread

        // ---- epoch-flag barrier across the 4 group members
        if (tid == 0) {
            __threadfence();   // agent-scope release of the published h
            __hip_atomic_store(&flags[wg * 16], t + 1,
                               __ATOMIC_RELEASE, __HIP_MEMORY_SCOPE_AGENT);
        }
        if (tid < 4) {
            const int peer = g + 64 * tid;
            while (__hip_atomic_load(&flags[peer * 16],
                                     __ATOMIC_ACQUIRE, __HIP_MEMORY_SCOPE_AGENT) < t + 1) {
                __builtin_amdgcn_s_sleep(1);
            }
        }
        __syncthreads();

        // ---- import full h for both batches
        if (tid < 512) {
            int p = (t + 1) & 1;
            int m = tid >> 8, j = tid & 255;
            h_lds[m][j] = __hip_atomic_load(&hbuf[((size_t)p * BB + (b0 + m)) * HH + j],
                                            __ATOMIC_RELAXED, __HIP_MEMORY_SCOPE_AGENT);
        }
        __syncthreads();
    }

    // ---- epilogue MLP, done by q==0 wg of each group for its 2 batches
    if (q == 0) {
        if (tid < 256) {
            int m = tid >> 7, j = tid & 127;
            const float4* w1p = reinterpret_cast<const float4*>(W1 + (size_t)j * HH);
            const float4* hp  = reinterpret_cast<const float4*>(&h_lds[m][0]);
            float s0 = 0.f, s1 = 0.f;
            #pragma unroll
            for (int k = 0; k < 64; ++k) {
                float4 wv = w1p[k], hv = hp[k];
                s0 = __builtin_fmaf(wv.x, hv.x, s0);
                s1 = __builtin_fmaf(wv.y, hv.y, s1);
                s0 = __builtin_fmaf(wv.z, hv.z, s0);
                s1 = __builtin_fmaf(wv.w, hv.w, s1);
            }
            float rv = fmaxf(s0 + s1 + b1[j], 0.f);
            part_lds[0][m * 128 + j] = rv * W2[j];
        }
        __syncthreads();
        if (tid < 2) {
            float y = b2[0];
            for (int k = 0; k < 128; ++k) y += part_lds[0][tid * 128 + k];
            out[b0 + tid] = y;
        }
    }
}

extern "C" void kernel_launch(void* const* d_in, const int* in_sizes, int n_in,
                              void* d_out, int out_size, void* d_ws, size_t ws_size,
                              hipStream_t stream) {
    const float* x    = (const float*)d_in[0];
    const float* W_ih = (const float*)d_in[1];
    const float* W_hh = (const float*)d_in[2];
    const float* b_ih = (const float*)d_in[3];
    const float* b_hh = (const float*)d_in[4];
    const float* W1   = (const float*)d_in[5];
    const float* b1   = (const float*)d_in[6];
    const float* W2   = (const float*)d_in[7];
    const float* b2   = (const float*)d_in[8];
    float* out  = (float*)d_out;

    int*   flagp = (int*)d_ws;                         // 16 KB (256 flags, stride 64B)
    float* hbuf  = (float*)((char*)d_ws + 16384);      // 2*128*256*4 = 256 KB

    // flags must be zero at every call (d_ws is not re-poisoned between replays)
    hipMemsetAsync(d_ws, 0, 16384, stream);

    void* args[] = {(void*)&x, (void*)&W_ih, (void*)&W_hh, (void*)&b_ih, (void*)&b_hh,
                    (void*)&W1, (void*)&b1, (void*)&W2, (void*)&b2,
                    (void*)&out, (void*)&flagp, (void*)&hbuf};
    hipLaunchCooperativeKernel((void*)lstm_coop, dim3(256), dim3(1024), args, 0, stream);
}

// Round 4
// 4712.266 us; speedup vs baseline: 3.0933x; 1.0558x over previous
//
#include <hip/hip_runtime.h>

#define TT 512
#define HH 256
#define BB 128

// 256 wgs x 1024 threads, cooperative. Group g (g = wg & 63) = wgs
// {g, g+64, g+128, g+192} (same XCD under round-robin dispatch), handles
// batches {2g, 2g+1}. Member q = wg >> 6 owns h elements [64q, 64q+64):
// gate rows G*256 + 64q + [0,64) for G in {i,f,g,o}. Thread holds
// 2 rows x 32-K-chunk of W_hh in 64 VGPRs.
//
// KEY: part_lds is deliberately oversized to push static LDS > 80KB so the
// backend's LDS-occupancy target drops to 1 wg/CU (4 waves/EU) -> VGPR
// budget 128 -> the 64 weight VGPRs stay resident (no scratch spill).
// Runtime cost is zero: cooperative launch has exactly 1 wg/CU anyway.
__global__ __launch_bounds__(1024)
__attribute__((amdgpu_waves_per_eu(4, 4)))
void lstm_coop(
    const float* __restrict__ x,      // [B,T]
    const float* __restrict__ W_ih,   // [1024]
    const float* __restrict__ W_hh,   // [1024,256]
    const float* __restrict__ b_ih,   // [1024]
    const float* __restrict__ b_hh,   // [1024]
    const float* __restrict__ W1,     // [128,256]
    const float* __restrict__ b1,     // [128]
    const float* __restrict__ W2,     // [128]
    const float* __restrict__ b2,     // [1]
    float* __restrict__ out,          // [B]
    int* __restrict__ flags,          // [256] stride-16 ints (epoch per wg)
    float* __restrict__ hbuf)         // [2][BB][HH]
{
    const int wg  = blockIdx.x;
    const int g   = wg & 63;          // group id (batch pair)
    const int q   = wg >> 6;          // member id 0..3
    const int tid = threadIdx.x;
    const int b0  = 2 * g;

    __shared__ float x_lds[2][TT];        // 4 KB
    __shared__ float h_lds[2][HH];        // 2 KB
    __shared__ float part_lds[96][HH];    // 96 KB (only rows 0..15 used; see note)
    __shared__ float pre_lds[2][HH];      // 2 KB

    // dot-phase mapping: s = k-chunk (8 chunks of 32), r2 = row-pair id
    const int s  = tid >> 7;          // 0..7
    const int r2 = tid & 127;         // 0..127 -> rows r2 and r2+128
    const int RA = ((r2 >> 6)    ) * HH + q * 64 + (r2 & 63);      // gates i/f
    const int RB = ((r2 >> 6) + 2) * HH + q * 64 + (r2 & 63);      // gates g/o

    // resident weights: W_hh[RA][32s..32s+31], W_hh[RB][...]
    float wa[32], wb[32];
    {
        const float4* pa = reinterpret_cast<const float4*>(W_hh + (size_t)RA * HH + 32 * s);
        const float4* pb = reinterpret_cast<const float4*>(W_hh + (size_t)RB * HH + 32 * s);
        #pragma unroll
        for (int k = 0; k < 8; ++k) {
            float4 va = pa[k], vb = pb[k];
            wa[4*k+0] = va.x; wa[4*k+1] = va.y; wa[4*k+2] = va.z; wa[4*k+3] = va.w;
            wb[4*k+0] = vb.x; wb[4*k+1] = vb.y; wb[4*k+2] = vb.z; wb[4*k+3] = vb.w;
        }
    }
    // make weight values opaque: cannot be rematerialized from W_hh
    #pragma unroll
    for (int k = 0; k < 32; ++k) {
        asm volatile("" : "+v"(wa[k]));
        asm volatile("" : "+v"(wb[k]));
    }

    // reduce-phase per-row constants (row = tid&255, used by tid<512)
    const int rr_row = tid & 255;
    const int RR = (rr_row >> 6) * HH + q * 64 + (rr_row & 63);
    const float wih_r  = W_ih[RR];
    const float bias_r = b_ih[RR] + b_hh[RR];

    // stage x for both batches
    {
        int m = tid >> 9, j = tid & 511;
        x_lds[m][j] = x[(size_t)(b0 + m) * TT + j];
    }
    if (tid < 512) h_lds[tid >> 8][tid & 255] = 0.0f;

    float c = 0.0f;                       // cell state for tid<128
    __syncthreads();

    for (int t = 0; t < TT; ++t) {
        // ---- dot: all 1024 threads, 128 fma each (weights in VGPRs)
        const float4* ha = reinterpret_cast<const float4*>(&h_lds[0][32 * s]);
        const float4* hb = reinterpret_cast<const float4*>(&h_lds[1][32 * s]);
        float aA0 = 0.f, aA1 = 0.f, bA0 = 0.f, bA1 = 0.f;
        #pragma unroll
        for (int k = 0; k < 8; ++k) {
            float4 h0 = ha[k];
            float4 h1 = hb[k];
            aA0 = __builtin_fmaf(wa[4*k+0], h0.x, aA0);
            aA0 = __builtin_fmaf(wa[4*k+1], h0.y, aA0);
            aA0 = __builtin_fmaf(wa[4*k+2], h0.z, aA0);
            aA0 = __builtin_fmaf(wa[4*k+3], h0.w, aA0);
            aA1 = __builtin_fmaf(wb[4*k+0], h0.x, aA1);
            aA1 = __builtin_fmaf(wb[4*k+1], h0.y, aA1);
            aA1 = __builtin_fmaf(wb[4*k+2], h0.z, aA1);
            aA1 = __builtin_fmaf(wb[4*k+3], h0.w, aA1);
            bA0 = __builtin_fmaf(wa[4*k+0], h1.x, bA0);
            bA0 = __builtin_fmaf(wa[4*k+1], h1.y, bA0);
            bA0 = __builtin_fmaf(wa[4*k+2], h1.z, bA0);
            bA0 = __builtin_fmaf(wa[4*k+3], h1.w, bA0);
            bA1 = __builtin_fmaf(wb[4*k+0], h1.x, bA1);
            bA1 = __builtin_fmaf(wb[4*k+1], h1.y, bA1);
            bA1 = __builtin_fmaf(wb[4*k+2], h1.z, bA1);
            bA1 = __builtin_fmaf(wb[4*k+3], h1.w, bA1);
        }
        part_lds[s][r2]           = aA0;   // batch0, row r2
        part_lds[s][r2 + 128]     = aA1;   // batch0, row r2+128
        part_lds[8 + s][r2]       = bA0;   // batch1
        part_lds[8 + s][r2 + 128] = bA1;
        __syncthreads();

        // ---- reduce over 8 k-chunks + input/bias: tid<512
        if (tid < 512) {
            int m = tid >> 8;
            float v = 0.f;
            #pragma unroll
            for (int ss = 0; ss < 8; ++ss) v += part_lds[m * 8 + ss][rr_row];
            pre_lds[m][rr_row] = v + __builtin_fmaf(x_lds[m][t], wih_r, bias_r);
        }
        __syncthreads();

        // ---- cell update: tid<128 (m = tid>>6, local elem l2 = tid&63)
        if (tid < 128) {
            int m  = tid >> 6;
            int l2 = tid & 63;
            float ig = pre_lds[m][l2];
            float fg = pre_lds[m][64 + l2];
            float gg = pre_lds[m][128 + l2];
            float og = pre_lds[m][192 + l2];
            ig = __builtin_amdgcn_rcpf(1.f + __expf(-ig));
            fg = __builtin_amdgcn_rcpf(1.f + __expf(-fg));
            og = __builtin_amdgcn_rcpf(1.f + __expf(-og));
            gg = 2.f * __builtin_amdgcn_rcpf(1.f + __expf(-2.f * gg)) - 1.f;
            c = __builtin_fmaf(fg, c, ig * gg);
            float th = 2.f * __builtin_amdgcn_rcpf(1.f + __expf(-2.f * c)) - 1.f;
            float hn = og * th;
            int e = q * 64 + l2;
            h_lds[m][e] = hn;
            int p = (t + 1) & 1;
            __hip_atomic_store(&hbuf[((size_t)p * BB + (b0 + m)) * HH + e], hn,
                               __ATOMIC_RELAXED, __HIP_MEMORY_SCOPE_AGENT);
        }
        __syncthreads();   // all h-stores issued and drained (vmcnt) per-thread

        // ---- epoch-flag barrier across the 4 group members
        if (tid == 0) {
            __threadfence();   // agent-scope release of the published h
            __hip_atomic_store(&flags[wg * 16], t + 1,
                               __ATOMIC_RELEASE, __HIP_MEMORY_SCOPE_AGENT);
        }
        if (tid < 4) {
            const int peer = g + 64 * tid;
            while (__hip_atomic_load(&flags[peer * 16],
                                     __ATOMIC_ACQUIRE, __HIP_MEMORY_SCOPE_AGENT) < t + 1) {
                __builtin_amdgcn_s_sleep(1);
            }
        }
        __syncthreads();

        // ---- import full h for both batches
        if (tid < 512) {
            int p = (t + 1) & 1;
            int m = tid >> 8, j = tid & 255;
            h_lds[m][j] = __hip_atomic_load(&hbuf[((size_t)p * BB + (b0 + m)) * HH + j],
                                            __ATOMIC_RELAXED, __HIP_MEMORY_SCOPE_AGENT);
        }
        __syncthreads();
    }

    // ---- epilogue MLP, done by q==0 wg of each group for its 2 batches
    if (q == 0) {
        if (tid < 256) {
            int m = tid >> 7, j = tid & 127;
            const float4* w1p = reinterpret_cast<const float4*>(W1 + (size_t)j * HH);
            const float4* hp  = reinterpret_cast<const float4*>(&h_lds[m][0]);
            float s0 = 0.f, s1 = 0.f;
            #pragma unroll
            for (int k = 0; k < 64; ++k) {
                float4 wv = w1p[k], hv = hp[k];
                s0 = __builtin_fmaf(wv.x, hv.x, s0);
                s1 = __builtin_fmaf(wv.y, hv.y, s1);
                s0 = __builtin_fmaf(wv.z, hv.z, s0);
                s1 = __builtin_fmaf(wv.w, hv.w, s1);
            }
            float rv = fmaxf(s0 + s1 + b1[j], 0.f);
            part_lds[0][m * 128 + j] = rv * W2[j];
        }
        __syncthreads();
        if (tid < 2) {
            float y = b2[0];
            for (int k = 0; k < 128; ++k) y += part_lds[0][tid * 128 + k];
            out[b0 + tid] = y;
        }
    }
}

extern "C" void kernel_launch(void* const* d_in, const int* in_sizes, int n_in,
                              void* d_out, int out_size, void* d_ws, size_t ws_size,
                              hipStream_t stream) {
    const float* x    = (const float*)d_in[0];
    const float* W_ih = (const float*)d_in[1];
    const float* W_hh = (const float*)d_in[2];
    const float* b_ih = (const float*)d_in[3];
    const float* b_hh = (const float*)d_in[4];
    const float* W1   = (const float*)d_in[5];
    const float* b1   = (const float*)d_in[6];
    const float* W2   = (const float*)d_in[7];
    const float* b2   = (const float*)d_in[8];
    float* out  = (float*)d_out;

    int*   flagp = (int*)d_ws;                         // 16 KB (256 flags, stride 64B)
    float* hbuf  = (float*)((char*)d_ws + 16384);      // 2*128*256*4 = 256 KB

    // flags must be zero at every call (d_ws is not re-poisoned between replays)
    hipMemsetAsync(d_ws, 0, 16384, stream);

    void* args[] = {(void*)&x, (void*)&W_ih, (void*)&W_hh, (void*)&b_ih, (void*)&b_hh,
                    (void*)&W1, (void*)&b1, (void*)&W2, (void*)&b2,
                    (void*)&out, (void*)&flagp, (void*)&hbuf};
    hipLaunchCooperativeKernel((void*)lstm_coop, dim3(256), dim3(1024), args, 0, stream);
}

// Round 5
// 1858.799 us; speedup vs baseline: 7.8419x; 2.5351x over previous
//
#include <hip/hip_runtime.h>

#define TT 512
#define HH 256
#define BB 128

typedef unsigned long long u64;

// 256 wgs x 1024 threads, cooperative, 1 wg/CU (forced by >80KB LDS).
// Group g (= wg & 31) = wgs {g, g+32, ..., g+224} -> all on XCD g%8 under
// round-robin dispatch. Group handles batches 4g..4g+3. Member q = wg>>5
// owns h elements [32q, 32q+32) (gate rows G*256 + 32q + [0,32)).
// Thread = (s = tid>>6: 16-wide K-chunk, r2 = tid&63: row pair) holds
// 2 rows x 16 K = 32 weight floats in VGPRs -> fits the 64-VGPR budget
// the backend insists on for 1024-thread blocks (rounds 2-4 post-mortem).
// Cross-CU exchange: single-round epoch-tagged 8B payloads {epoch, h},
// relaxed agent-scope atomics, no fences; poll until epoch >= t+1.
__global__ __launch_bounds__(1024)
__attribute__((amdgpu_waves_per_eu(4, 4)))
void lstm_coop(
    const float* __restrict__ x,      // [B,T]
    const float* __restrict__ W_ih,   // [1024]
    const float* __restrict__ W_hh,   // [1024,256]
    const float* __restrict__ b_ih,   // [1024]
    const float* __restrict__ b_hh,   // [1024]
    const float* __restrict__ W1,     // [128,256]
    const float* __restrict__ b1,     // [128]
    const float* __restrict__ W2,     // [128]
    const float* __restrict__ b2,     // [1]
    float* __restrict__ out,          // [B]
    u64* __restrict__ hpair)          // [2][BB][HH] {epoch,h}
{
    const int wg  = blockIdx.x;
    const int g   = wg & 31;          // group id
    const int q   = wg >> 5;          // member 0..7
    const int tid = threadIdx.x;
    const int b0  = 4 * g;

    __shared__ float x_lds[4][TT];           // 8 KB
    __shared__ float h_lds[4][HH];           // 4 KB
    __shared__ float part_lds[44][128][4];   // 88 KB (rows 0..15 used; oversize -> 1 wg/CU)
    __shared__ float pre_lds[128][4];        // 2 KB
    __shared__ float red_lds[4][128];        // 2 KB

    const int s  = tid >> 6;          // 0..15 : K-chunk of 16
    const int r2 = tid & 63;          // row pair: local rows r2 and r2+64
    const int lA = r2, lB = r2 + 64;
    const int RA = (lA >> 5) * HH + q * 32 + (lA & 31);
    const int RB = (lB >> 5) * HH + q * 32 + (lB & 31);

    // resident weights: 2 rows x 16 K = 32 VGPRs
    float wA[16], wB[16];
    {
        const float4* pa = reinterpret_cast<const float4*>(W_hh + (size_t)RA * HH + 16 * s);
        const float4* pb = reinterpret_cast<const float4*>(W_hh + (size_t)RB * HH + 16 * s);
        #pragma unroll
        for (int k = 0; k < 4; ++k) {
            float4 va = pa[k], vb = pb[k];
            wA[4*k+0] = va.x; wA[4*k+1] = va.y; wA[4*k+2] = va.z; wA[4*k+3] = va.w;
            wB[4*k+0] = vb.x; wB[4*k+1] = vb.y; wB[4*k+2] = vb.z; wB[4*k+3] = vb.w;
        }
    }
    #pragma unroll
    for (int k = 0; k < 16; ++k) {
        asm volatile("" : "+v"(wA[k]));
        asm volatile("" : "+v"(wB[k]));
    }

    // reduce-phase constants (thread lr covers local gate row lr, lr = tid&127)
    const int lr = tid & 127;
    const int RR = (lr >> 5) * HH + q * 32 + (lr & 31);
    const float wih_r  = W_ih[RR];
    const float bias_r = b_ih[RR] + b_hh[RR];

    // stage x for 4 batches (2048 elems, 2 per thread)
    #pragma unroll
    for (int u = 0; u < 2; ++u) {
        int idx = tid + u * 1024;
        int m = idx >> 9, j = idx & 511;
        x_lds[m][j] = x[(size_t)(b0 + m) * TT + j];
    }
    // h init (4*256 = 1024 elems, 1 per thread)
    h_lds[tid >> 8][tid & 255] = 0.0f;

    float c = 0.0f;                   // cell state for tid<128
    __syncthreads();

    for (int t = 0; t < TT; ++t) {
        // ---- dot: all 1024 threads, 2 rows x 16 K x 4 batches = 128 FMA
        float accA[4], accB[4];
        #pragma unroll
        for (int m = 0; m < 4; ++m) {
            const float4* hm = reinterpret_cast<const float4*>(&h_lds[m][16 * s]);
            float4 h0 = hm[0], h1 = hm[1], h2 = hm[2], h3 = hm[3];
            float aa, ab;
            aa = wA[0] * h0.x;               ab = wB[0] * h0.x;
            aa = __builtin_fmaf(wA[1],  h0.y, aa); ab = __builtin_fmaf(wB[1],  h0.y, ab);
            aa = __builtin_fmaf(wA[2],  h0.z, aa); ab = __builtin_fmaf(wB[2],  h0.z, ab);
            aa = __builtin_fmaf(wA[3],  h0.w, aa); ab = __builtin_fmaf(wB[3],  h0.w, ab);
            aa = __builtin_fmaf(wA[4],  h1.x, aa); ab = __builtin_fmaf(wB[4],  h1.x, ab);
            aa = __builtin_fmaf(wA[5],  h1.y, aa); ab = __builtin_fmaf(wB[5],  h1.y, ab);
            aa = __builtin_fmaf(wA[6],  h1.z, aa); ab = __builtin_fmaf(wB[6],  h1.z, ab);
            aa = __builtin_fmaf(wA[7],  h1.w, aa); ab = __builtin_fmaf(wB[7],  h1.w, ab);
            aa = __builtin_fmaf(wA[8],  h2.x, aa); ab = __builtin_fmaf(wB[8],  h2.x, ab);
            aa = __builtin_fmaf(wA[9],  h2.y, aa); ab = __builtin_fmaf(wB[9],  h2.y, ab);
            aa = __builtin_fmaf(wA[10], h2.z, aa); ab = __builtin_fmaf(wB[10], h2.z, ab);
            aa = __builtin_fmaf(wA[11], h2.w, aa); ab = __builtin_fmaf(wB[11], h2.w, ab);
            aa = __builtin_fmaf(wA[12], h3.x, aa); ab = __builtin_fmaf(wB[12], h3.x, ab);
            aa = __builtin_fmaf(wA[13], h3.y, aa); ab = __builtin_fmaf(wB[13], h3.y, ab);
            aa = __builtin_fmaf(wA[14], h3.z, aa); ab = __builtin_fmaf(wB[14], h3.z, ab);
            aa = __builtin_fmaf(wA[15], h3.w, aa); ab = __builtin_fmaf(wB[15], h3.w, ab);
            accA[m] = aa; accB[m] = ab;
        }
        *reinterpret_cast<float4*>(&part_lds[s][lA][0]) =
            make_float4(accA[0], accA[1], accA[2], accA[3]);
        *reinterpret_cast<float4*>(&part_lds[s][lB][0]) =
            make_float4(accB[0], accB[1], accB[2], accB[3]);
        __syncthreads();

        // ---- reduce over 16 K-chunks + input/bias: threads 0..127 (row lr)
        if (tid < 128) {
            float4 acc = make_float4(0.f, 0.f, 0.f, 0.f);
            #pragma unroll
            for (int ss = 0; ss < 16; ++ss) {
                float4 v = *reinterpret_cast<const float4*>(&part_lds[ss][lr][0]);
                acc.x += v.x; acc.y += v.y; acc.z += v.z; acc.w += v.w;
            }
            float4 pre;
            pre.x = acc.x + __builtin_fmaf(x_lds[0][t], wih_r, bias_r);
            pre.y = acc.y + __builtin_fmaf(x_lds[1][t], wih_r, bias_r);
            pre.z = acc.z + __builtin_fmaf(x_lds[2][t], wih_r, bias_r);
            pre.w = acc.w + __builtin_fmaf(x_lds[3][t], wih_r, bias_r);
            *reinterpret_cast<float4*>(&pre_lds[lr][0]) = pre;
        }
        __syncthreads();

        const int p = (t + 1) & 1;

        // ---- cell update + publish: threads 0..127 -> (m = tid&3, l = tid>>2)
        if (tid < 128) {
            const int m = tid & 3;
            const int l = tid >> 2;
            float ig = pre_lds[l     ][m];
            float fg = pre_lds[32 + l][m];
            float gg = pre_lds[64 + l][m];
            float og = pre_lds[96 + l][m];
            ig = __builtin_amdgcn_rcpf(1.f + __expf(-ig));
            fg = __builtin_amdgcn_rcpf(1.f + __expf(-fg));
            og = __builtin_amdgcn_rcpf(1.f + __expf(-og));
            gg = 2.f * __builtin_amdgcn_rcpf(1.f + __expf(-2.f * gg)) - 1.f;
            c = __builtin_fmaf(fg, c, ig * gg);
            float th = 2.f * __builtin_amdgcn_rcpf(1.f + __expf(-2.f * c)) - 1.f;
            float hn = og * th;
            const int e = q * 32 + l;
            u64 pk = ((u64)(unsigned)(t + 1) << 32) | (u64)__float_as_uint(hn);
            __hip_atomic_store(&hpair[((size_t)p * BB + (b0 + m)) * HH + e], pk,
                               __ATOMIC_RELAXED, __HIP_MEMORY_SCOPE_AGENT);
        }

        // ---- import/poll: every thread owns one (m,j) pair
        {
            const int m = tid >> 8, j = tid & 255;
            const u64* src = &hpair[((size_t)p * BB + (b0 + m)) * HH + j];
            u64 v = __hip_atomic_load(src, __ATOMIC_RELAXED, __HIP_MEMORY_SCOPE_AGENT);
            while ((unsigned)(v >> 32) < (unsigned)(t + 1)) {
                v = __hip_atomic_load(src, __ATOMIC_RELAXED, __HIP_MEMORY_SCOPE_AGENT);
            }
            h_lds[m][j] = __uint_as_float((unsigned)v);
        }
        __syncthreads();
    }

    // ---- epilogue MLP: wg q==0 of each group handles its 4 batches
    if (q == 0) {
        if (tid < 512) {
            const int m = tid >> 7, j = tid & 127;
            const float4* w1p = reinterpret_cast<const float4*>(W1 + (size_t)j * HH);
            const float4* hp  = reinterpret_cast<const float4*>(&h_lds[m][0]);
            float s0 = 0.f, s1 = 0.f, s2 = 0.f, s3 = 0.f;
            #pragma unroll
            for (int k = 0; k < 64; ++k) {
                float4 wv = w1p[k], hv = hp[k];
                s0 = __builtin_fmaf(wv.x, hv.x, s0);
                s1 = __builtin_fmaf(wv.y, hv.y, s1);
                s2 = __builtin_fmaf(wv.z, hv.z, s2);
                s3 = __builtin_fmaf(wv.w, hv.w, s3);
            }
            float rv = fmaxf((s0 + s1) + (s2 + s3) + b1[j], 0.f);
            red_lds[m][j] = rv * W2[j];
        }
        __syncthreads();
        if (tid < 4) {
            float y = b2[0];
            for (int k = 0; k < 128; ++k) y += red_lds[tid][k];
            out[b0 + tid] = y;
        }
    }
}

extern "C" void kernel_launch(void* const* d_in, const int* in_sizes, int n_in,
                              void* d_out, int out_size, void* d_ws, size_t ws_size,
                              hipStream_t stream) {
    const float* x    = (const float*)d_in[0];
    const float* W_ih = (const float*)d_in[1];
    const float* W_hh = (const float*)d_in[2];
    const float* b_ih = (const float*)d_in[3];
    const float* b_hh = (const float*)d_in[4];
    const float* W1   = (const float*)d_in[5];
    const float* b1   = (const float*)d_in[6];
    const float* W2   = (const float*)d_in[7];
    const float* b2   = (const float*)d_in[8];
    float* out  = (float*)d_out;

    u64* hpair = (u64*)d_ws;                    // [2][128][256] x 8B = 512 KB

    // epochs must be 0 at every call (d_ws keeps state across graph replays)
    hipMemsetAsync(d_ws, 0, (size_t)2 * BB * HH * sizeof(u64), stream);

    void* args[] = {(void*)&x, (void*)&W_ih, (void*)&W_hh, (void*)&b_ih, (void*)&b_hh,
                    (void*)&W1, (void*)&b1, (void*)&W2, (void*)&b2,
                    (void*)&out, (void*)&hpair};
    hipLaunchCooperativeKernel((void*)lstm_coop, dim3(256), dim3(1024), args, 0, stream);
}